// Round 7
// baseline (177.025 us; speedup 1.0000x reference)
//
#include <hip/hip_runtime.h>
#include <hip/hip_bf16.h>

// ---- problem constants ----
#define C_SZ   3
#define IMG_SZ 512
// per (c,g) GEMM: M = 64*32 = 2048, K = 256, N = 256
// block: BM=32 x BN=256, 4 waves, each wave 32x64. 64 mtiles x 96 cg = 6144 blocks.

typedef short  short8 __attribute__((ext_vector_type(8)));   // 8 bf16 (4 VGPR)
typedef float  f32x4  __attribute__((ext_vector_type(4)));
typedef unsigned short u16;
typedef u16    u16x8  __attribute__((ext_vector_type(8)));

__device__ __forceinline__ u16 f2bf(float f) {
    unsigned u = __float_as_uint(f);
    u += 0x7FFFu + ((u >> 16) & 1u);          // RNE
    return (u16)(u >> 16);
}

// packed f32->bf16 pair (v_cvt_pk_bf16_f32 via compiler intrinsic, RNE)
__device__ __forceinline__ unsigned pkbf(float lo, float hi) {
    union { __hip_bfloat162 h; unsigned u; } cv;
    cv.h = __float22bfloat162_rn(make_float2(lo, hi));
    return cv.u;
}

__device__ __forceinline__ float tanh_fast(float v) {
    float e = __expf(2.f * v);
    return 1.f - 2.f * __builtin_amdgcn_rcpf(e + 1.f);
}

// async 16B global->LDS DMA (lane i lands at ldsbase + i*16)
__device__ __forceinline__ void gload_lds16(const float* g, float* l) {
    __builtin_amdgcn_global_load_lds(
        (const __attribute__((address_space(1))) void*)g,
        (__attribute__((address_space(3))) void*)l, 16, 0, 0);
}

// order-pinned 16B global->VGPR load (counts in vmcnt exactly where issued)
__device__ __forceinline__ short8 gload_b128(const u16* p) {
    short8 d;
    asm volatile("global_load_dwordx4 %0, %1, off"
                 : "=v"(d) : "v"(p) : "memory");
    return d;
}

// ---------- prep: wt3[cg][kb][kg][n][e] = bf16(w[cg][kb*32+kg*8+e][n]) ----------
__global__ __launch_bounds__(256)
void prep_wt(const float* __restrict__ w, u16* __restrict__ wt) {
    const int cg = blockIdx.x;        // 0..95
    const int kb = blockIdx.y;        // 0..7
    __shared__ float T[32][260];      // +4 pad: conflict-free column gather
    const int tid = threadIdx.x;
    const float* wb = w + (size_t)cg * 65536 + (size_t)kb * 32 * 256;
    #pragma unroll
    for (int pass = 0; pass < 8; ++pass) {
        int q = pass * 256 + tid;
        int pl = q >> 6, o4 = (q & 63) * 4;
        float4 v = *reinterpret_cast<const float4*>(wb + (size_t)pl * 256 + o4);
        T[pl][o4 + 0] = v.x; T[pl][o4 + 1] = v.y;
        T[pl][o4 + 2] = v.z; T[pl][o4 + 3] = v.w;
    }
    __syncthreads();
    u16* dst = wt + ((size_t)cg * 8 + kb) * 8192;
    #pragma unroll
    for (int h0 = 0; h0 < 4; ++h0) {
        int h = h0 * 256 + tid;
        int kg = h >> 8, n = h & 255;
        u16x8 v;
        #pragma unroll
        for (int e = 0; e < 8; ++e) v[e] = f2bf(T[kg * 8 + e][n]);
        *reinterpret_cast<u16x8*>(dst + (size_t)kg * 2048 + n * 8) = v;
    }
}

// ---------- main GEMM: BM=32 x BN=256, 4 waves (each 32x64) ----------
// Small acc (2x4) -> low VGPR -> 5-6 waves/SIMD occupancy. A staged via async
// DMA (1 inst/wave/phase, XOR-swizzled source+read), B asm-pinned from L2.
__global__ __launch_bounds__(256, 5)
void obf_mfma(const float* __restrict__ x,
              const u16*  __restrict__ wt,
              const float* __restrict__ bias,
              const int*  __restrict__ perm,
              float* __restrict__ out)
{
    // bijective XCD swizzle: 6144 = 8 XCDs x 768
    const int bid  = blockIdx.x;
    const int sbid = (bid & 7) * 768 + (bid >> 3);
    const int mtile = sbid & 63;      // 0..63
    const int cg    = sbid >> 6;      // 0..95
    const int c = cg >> 5, g = cg & 31;
    const int tid  = threadIdx.x;
    const int lane = tid & 63, wv = tid >> 6;
    const int r = lane & 15, kg = lane >> 4;

    __shared__ float As[3][1024];     // ring: 3 x 4KB (32 rows x 32 floats, 128B rows)

    int cp = 0;
    #pragma unroll
    for (int i = 0; i < C_SZ; ++i) if (perm[i] == c) cp = i;

    // A staging source: 1 DMA inst/wave/phase. lane l -> local row lr = wv*8+(l>>3),
    // phys chunk pch = l&7, logical chunk lch = pch ^ (lr&7)  (both-sides involution).
    const float* g_src;
    {
        int lr   = wv * 8 + (lane >> 3);
        int lch  = (lane & 7) ^ (lr & 7);
        int R    = mtile * 32 + lr;
        int b    = R >> 5, nh = R & 31, nw = (g - nh) & 31;
        g_src = x + (((size_t)(b * C_SZ + c) * IMG_SZ + nh * 16 + (lch >> 2)) * IMG_SZ
                     + nw * 16 + (lch & 3) * 4);
    }
    // B fragment source: wave wv owns cols wv*64..+63
    const u16* bsrc = wt + (size_t)cg * 65536 + kg * 2048 + (size_t)(wv * 64 + r) * 8;

    f32x4 acc[2][4] = {};
    short8 bv[4];

#define STAGE_A(t) do {                                                   \
        float* d_ = &As[(t) % 3][0] + wv * 256;                           \
        gload_lds16(g_src + (size_t)(t) * 1024, d_);                      \
    } while (0)

    // ---- prologue ----
    STAGE_A(0);

    #pragma unroll
    for (int t = 0; t < 8; ++t) {
        // B(t): 4 pinned loads (L2-resident, latency hidden by TLP)
        #pragma unroll
        for (int ni = 0; ni < 4; ++ni)
            bv[ni] = gload_b128(bsrc + (size_t)t * 8192 + ni * 128);
        if (t < 7) {
            STAGE_A(t + 1);                               // 1 DMA
            asm volatile("s_waitcnt vmcnt(1)" ::: "memory");  // drain A(t)+B(t)
        } else {
            asm volatile("s_waitcnt vmcnt(0)" ::: "memory");
        }
        __builtin_amdgcn_sched_barrier(0);
        __builtin_amdgcn_s_barrier();

        const float* lb = &As[t % 3][0];
        #pragma unroll
        for (int mi = 0; mi < 2; ++mi) {
            const int rowoff = (mi * 16 + r) * 32;
            f32x4 v0 = *reinterpret_cast<const f32x4*>(
                lb + rowoff + (((2 * kg)     ^ (r & 7)) * 4));
            f32x4 v1 = *reinterpret_cast<const f32x4*>(
                lb + rowoff + (((2 * kg + 1) ^ (r & 7)) * 4));
            union { short8 s; uint4 u; } A_;
            A_.u.x = pkbf(v0[0], v0[1]);
            A_.u.y = pkbf(v0[2], v0[3]);
            A_.u.z = pkbf(v1[0], v1[1]);
            A_.u.w = pkbf(v1[2], v1[3]);
            #pragma unroll
            for (int ni = 0; ni < 4; ++ni)
                acc[mi][ni] = __builtin_amdgcn_mfma_f32_16x16x32_bf16(
                    A_.s, bv[ni], acc[mi][ni], 0, 0, 0);
        }
        // next iteration's barrier separates compute(t) from STAGE_A(t+3)'s reuse
    }
#undef STAGE_A

    // ---- epilogue: bias + tanh + un-patch + channel permute ----
    const int cc = r;
    float bs[4];
    #pragma unroll
    for (int ni = 0; ni < 4; ++ni)
        bs[ni] = bias[(size_t)cg * 256 + wv * 64 + ni * 16 + cc];

    #pragma unroll
    for (int mi = 0; mi < 2; ++mi) {
        #pragma unroll
        for (int reg = 0; reg < 4; ++reg) {
            const int ml = mi * 16 + kg * 4 + reg;
            const int mg = mtile * 32 + ml;
            const int b  = mg >> 5, nh = mg & 31, nw = (g - nh) & 31;
            float* orow = out + ((size_t)(b * C_SZ + cp) * IMG_SZ + nh * 16) * IMG_SZ
                              + nw * 16 + cc;
            #pragma unroll
            for (int ni = 0; ni < 4; ++ni) {
                const int rp = wv * 4 + ni;          // patch-local row
                orow[(size_t)rp * IMG_SZ] = tanh_fast(acc[mi][ni][reg] + bs[ni]);
            }
        }
    }
}

extern "C" void kernel_launch(void* const* d_in, const int* in_sizes, int n_in,
                              void* d_out, int out_size, void* d_ws, size_t ws_size,
                              hipStream_t stream) {
    const float* x    = (const float*)d_in[0];
    const float* w    = (const float*)d_in[1];
    const float* bias = (const float*)d_in[2];
    const int*   perm = (const int*)d_in[3];
    float* out = (float*)d_out;
    u16*   wt  = (u16*)d_ws;          // 96*65536*2 = 12.6 MB scratch

    dim3 pgrid(C_SZ * 32, 8, 1);      // (96,8)
    prep_wt<<<pgrid, 256, 0, stream>>>(w, wt);

    obf_mfma<<<6144, 256, 0, stream>>>(x, wt, bias, perm, out);
}

// Round 8
// 132.477 us; speedup vs baseline: 1.3363x; 1.3363x over previous
//
#include <hip/hip_runtime.h>

// ---- problem constants ----
#define C_SZ   3
#define IMG_SZ 512
// per (c,g) GEMM: M = 64*32 = 2048, K = 256, N = 256

typedef short  short8 __attribute__((ext_vector_type(8)));   // 8 bf16 (4 VGPR)
typedef float  f32x4  __attribute__((ext_vector_type(4)));
typedef unsigned short u16;
typedef u16    u16x8  __attribute__((ext_vector_type(8)));

__device__ __forceinline__ u16 f2bf(float f) {
    unsigned u = __float_as_uint(f);
    u += 0x7FFFu + ((u >> 16) & 1u);          // round-to-nearest-even
    return (u16)(u >> 16);
}

__device__ __forceinline__ float tanh_fast(float v) {
    float e = __expf(2.f * v);
    return 1.f - 2.f * __builtin_amdgcn_rcpf(e + 1.f);
}

// async 16B global->LDS DMA (lane i of the wave lands at ldsbase + i*16)
__device__ __forceinline__ void gload_lds16(const float* g, float* l) {
    __builtin_amdgcn_global_load_lds(
        (const __attribute__((address_space(1))) void*)g,
        (__attribute__((address_space(3))) void*)l, 16, 0, 0);
}

// order-pinned 16B global->VGPR load (counts in vmcnt exactly where issued)
__device__ __forceinline__ short8 gload_b128(const u16* p) {
    short8 d;
    asm volatile("global_load_dwordx4 %0, %1, off"
                 : "=v"(d) : "v"(p) : "memory");
    return d;
}

// ---------- prep: wt3[cg][kb][kg][n][e] = bf16(w[cg][kb*32+kg*8+e][n]) ----------
__global__ __launch_bounds__(256)
void prep_wt(const float* __restrict__ w, u16* __restrict__ wt) {
    const int cg = blockIdx.x;        // 0..95
    const int kb = blockIdx.y;        // 0..7
    __shared__ float T[32][260];      // +4 pad: conflict-free column gather
    const int tid = threadIdx.x;
    const float* wb = w + (size_t)cg * 65536 + (size_t)kb * 32 * 256;
    #pragma unroll
    for (int pass = 0; pass < 8; ++pass) {
        int q = pass * 256 + tid;
        int pl = q >> 6, o4 = (q & 63) * 4;
        float4 v = *reinterpret_cast<const float4*>(wb + (size_t)pl * 256 + o4);
        T[pl][o4 + 0] = v.x; T[pl][o4 + 1] = v.y;
        T[pl][o4 + 2] = v.z; T[pl][o4 + 3] = v.w;
    }
    __syncthreads();
    u16* dst = wt + ((size_t)cg * 8 + kb) * 8192;
    #pragma unroll
    for (int h0 = 0; h0 < 4; ++h0) {
        int h = h0 * 256 + tid;
        int kg = h >> 8, n = h & 255;
        u16x8 v;
        #pragma unroll
        for (int e = 0; e < 8; ++e) v[e] = f2bf(T[kg * 8 + e][n]);
        *reinterpret_cast<u16x8*>(dst + (size_t)kg * 2048 + n * 8) = v;
    }
}

// ---------- main GEMM: BM=64 x BN=256, 4 waves (each 64x64) ----------
// IDENTICAL dataflow to round 6 (async-DMA A ring, asm-pinned B, counted vmcnt).
// ONLY change: block-index mapping. g now varies FASTEST among co-resident
// blocks with (c, mtile) fixed, so a resident cohort of 32 g-blocks reads/writes
// COMPLETE contiguous image rows (DRAM row-buffer friendly) instead of 64B
// diagonal granules, and its wt working set (one channel, 4MB bf16) is
// exactly L2-per-XCD resident.
__global__ __launch_bounds__(256)
void obf_mfma(const float* __restrict__ x,
              const u16*  __restrict__ wt,
              const float* __restrict__ bias,
              const int*  __restrict__ perm,
              float* __restrict__ out)
{
    // bijective: 3072 = 8 xcd x 12 slots x 32 g
    const int bid  = blockIdx.x;
    const int xcd  = bid & 7;
    const int i    = bid >> 3;        // 0..383 within XCD
    const int g    = i & 31;          // fastest: cohort spans all 32 diagonals
    const int s    = xcd * 12 + (i >> 5);   // 0..95 = (c, mtile)
    const int c    = s >> 5;
    const int mtile = s & 31;
    const int cg   = c * 32 + g;

    const int tid  = threadIdx.x;
    const int lane = tid & 63, wv = tid >> 6;
    const int r = lane & 15, kg = lane >> 4;

    __shared__ float As[3][2048];     // 3 x 8KB ring; rows = 32 floats (128B)

    int cp = 0;
    #pragma unroll
    for (int ii = 0; ii < C_SZ; ++ii) if (perm[ii] == c) cp = ii;

    // staging: thread owns physical chunks q0 = wv*128+lane, q1 = q0+64.
    // chunk q -> row = q>>3, pos = q&7, logical k-chunk lpos = pos ^ (row&7).
    const float* g_src[2];
    #pragma unroll
    for (int j = 0; j < 2; ++j) {
        int q    = wv * 128 + j * 64 + lane;
        int row  = q >> 3;
        int lpos = (q & 7) ^ (row & 7);
        int mg   = mtile * 64 + row;
        int b    = mg >> 5, nh = mg & 31, nw = (g - nh) & 31;
        g_src[j] = x + (((size_t)(b * C_SZ + c) * IMG_SZ + nh * 16 + (lpos >> 2)) * IMG_SZ
                        + nw * 16 + (lpos & 3) * 4);
    }
    // B fragment source (lane-contiguous 16B per (ks,ni))
    const u16* bsrc = wt + (size_t)cg * 65536 + kg * 2048 + (size_t)(wv * 64 + r) * 8;

    // swizzled ds_read float offsets (involution of the source swizzle)
    const int p0 = (((2 * kg)     ^ (r & 7)) * 4);
    const int p1 = (((2 * kg + 1) ^ (r & 7)) * 4);
    const int rbase = r * 32;

    f32x4 acc[4][4] = {};
    short8 bv[2][4];                  // ping-pong, all indices literal after unroll

#define STAGE_A(t) do {                                                \
        float* d_ = &As[(t) % 3][0] + wv * 512;                        \
        gload_lds16(g_src[0] + (size_t)(t) * 1024, d_);                \
        gload_lds16(g_src[1] + (size_t)(t) * 1024, d_ + 256);          \
    } while (0)

    // ---- prologue: stage 0 in flight ----
    STAGE_A(0);
    #pragma unroll
    for (int ni = 0; ni < 4; ++ni)
        bv[0][ni] = gload_b128(bsrc + ni * 128);

    #pragma unroll
    for (int t = 0; t < 8; ++t) {
        if (t < 7) {
            STAGE_A(t + 1);                           // 2 DMA
            #pragma unroll
            for (int ni = 0; ni < 4; ++ni)            // 4 pinned loads
                bv[(t + 1) & 1][ni] = gload_b128(bsrc + (t + 1) * 8192 + ni * 128);
            asm volatile("s_waitcnt vmcnt(6)" ::: "memory");  // drain stage t only
        } else {
            asm volatile("s_waitcnt vmcnt(0)" ::: "memory");
        }
        __builtin_amdgcn_sched_barrier(0);
        __builtin_amdgcn_s_barrier();

        const float* lb = &As[t % 3][0];
        #pragma unroll
        for (int mi = 0; mi < 4; ++mi) {
            f32x4 v0 = *reinterpret_cast<const f32x4*>(lb + mi * 512 + rbase + p0);
            f32x4 v1 = *reinterpret_cast<const f32x4*>(lb + mi * 512 + rbase + p1);
            short8 af;
            af[0] = (short)f2bf(v0[0]); af[1] = (short)f2bf(v0[1]);
            af[2] = (short)f2bf(v0[2]); af[3] = (short)f2bf(v0[3]);
            af[4] = (short)f2bf(v1[0]); af[5] = (short)f2bf(v1[1]);
            af[6] = (short)f2bf(v1[2]); af[7] = (short)f2bf(v1[3]);
            #pragma unroll
            for (int ni = 0; ni < 4; ++ni)
                acc[mi][ni] = __builtin_amdgcn_mfma_f32_16x16x32_bf16(
                    af, bv[t & 1][ni], acc[mi][ni], 0, 0, 0);
        }
    }
#undef STAGE_A

    // ---- epilogue: bias + tanh + un-patch + channel permute ----
    const int cc = lane & 15;
    float bs[4];
    #pragma unroll
    for (int ni = 0; ni < 4; ++ni)
        bs[ni] = bias[(size_t)cg * 256 + wv * 64 + ni * 16 + cc];

    #pragma unroll
    for (int mi = 0; mi < 4; ++mi) {
        #pragma unroll
        for (int reg = 0; reg < 4; ++reg) {
            const int ml = mi * 16 + kg * 4 + reg;
            const int mg = mtile * 64 + ml;
            const int b  = mg >> 5, nh = mg & 31, nw = (g - nh) & 31;
            float* orow = out + ((size_t)(b * C_SZ + cp) * IMG_SZ + nh * 16) * IMG_SZ
                              + nw * 16 + cc;
            #pragma unroll
            for (int ni = 0; ni < 4; ++ni) {
                const int rp = wv * 4 + ni;          // patch-local row
                orow[(size_t)rp * IMG_SZ] = tanh_fast(acc[mi][ni][reg] + bs[ni]);
            }
        }
    }
}

extern "C" void kernel_launch(void* const* d_in, const int* in_sizes, int n_in,
                              void* d_out, int out_size, void* d_ws, size_t ws_size,
                              hipStream_t stream) {
    const float* x    = (const float*)d_in[0];
    const float* w    = (const float*)d_in[1];
    const float* bias = (const float*)d_in[2];
    const int*   perm = (const int*)d_in[3];
    float* out = (float*)d_out;
    u16*   wt  = (u16*)d_ws;          // 96*65536*2 = 12.6 MB scratch

    dim3 pgrid(C_SZ * 32, 8, 1);      // (96,8)
    prep_wt<<<pgrid, 256, 0, stream>>>(w, wt);

    obf_mfma<<<3072, 256, 0, stream>>>(x, wt, bias, perm, out);
}

// Round 9
// 132.380 us; speedup vs baseline: 1.3373x; 1.0007x over previous
//
#include <hip/hip_runtime.h>

// ---- problem constants ----
#define C_SZ   3
#define IMG_SZ 512
// per (c,g) GEMM: M = 64*32 = 2048, K = 256, N = 256

typedef short  short8 __attribute__((ext_vector_type(8)));   // 8 bf16 (4 VGPR)
typedef float  f32x4  __attribute__((ext_vector_type(4)));
typedef unsigned short u16;
typedef u16    u16x8  __attribute__((ext_vector_type(8)));

__device__ __forceinline__ u16 f2bf(float f) {
    unsigned u = __float_as_uint(f);
    u += 0x7FFFu + ((u >> 16) & 1u);          // round-to-nearest-even
    return (u16)(u >> 16);
}

__device__ __forceinline__ float tanh_fast(float v) {
    float e = __expf(2.f * v);
    return 1.f - 2.f * __builtin_amdgcn_rcpf(e + 1.f);
}

// async 16B global->LDS DMA (lane i of the wave lands at ldsbase + i*16)
__device__ __forceinline__ void gload_lds16(const float* g, float* l) {
    __builtin_amdgcn_global_load_lds(
        (const __attribute__((address_space(1))) void*)g,
        (__attribute__((address_space(3))) void*)l, 16, 0, 0);
}

// order-pinned 16B global->VGPR load (counts in vmcnt exactly where issued)
__device__ __forceinline__ short8 gload_b128(const u16* p) {
    short8 d;
    asm volatile("global_load_dwordx4 %0, %1, off"
                 : "=v"(d) : "v"(p) : "memory");
    return d;
}

// ---------- prep: wt3[cg][kb][kg][n][e] = bf16(w[cg][kb*32+kg*8+e][n]) ----------
__global__ __launch_bounds__(256)
void prep_wt(const float* __restrict__ w, u16* __restrict__ wt) {
    const int cg = blockIdx.x;        // 0..95
    const int kb = blockIdx.y;        // 0..7
    __shared__ float T[32][260];      // +4 pad: conflict-free column gather
    const int tid = threadIdx.x;
    const float* wb = w + (size_t)cg * 65536 + (size_t)kb * 32 * 256;
    #pragma unroll
    for (int pass = 0; pass < 8; ++pass) {
        int q = pass * 256 + tid;
        int pl = q >> 6, o4 = (q & 63) * 4;
        float4 v = *reinterpret_cast<const float4*>(wb + (size_t)pl * 256 + o4);
        T[pl][o4 + 0] = v.x; T[pl][o4 + 1] = v.y;
        T[pl][o4 + 2] = v.z; T[pl][o4 + 3] = v.w;
    }
    __syncthreads();
    u16* dst = wt + ((size_t)cg * 8 + kb) * 8192;
    #pragma unroll
    for (int h0 = 0; h0 < 4; ++h0) {
        int h = h0 * 256 + tid;
        int kg = h >> 8, n = h & 255;
        u16x8 v;
        #pragma unroll
        for (int e = 0; e < 8; ++e) v[e] = f2bf(T[kg * 8 + e][n]);
        *reinterpret_cast<u16x8*>(dst + (size_t)kg * 2048 + n * 8) = v;
    }
}

// ---------- main GEMM: BM=64 x BN=256, 4 waves (each 64x64) ----------
// Round-8 dataflow + g-fastest cohort remap, deepened to prefetch distance 2:
// A: async-DMA into 4-buffer LDS ring, 2 stages in flight.
// B: fragment-ordered wt, asm-pinned loads, 1 stage ahead (ping-pong regs).
// vmcnt schedule (issue order per iter: B(t+1) then A(t+2)):
//   t=0:6, t=1..5:8, t=6:6, t=7:0  -- never drains the in-flight stages.
__global__ __launch_bounds__(256)
void obf_mfma(const float* __restrict__ x,
              const u16*  __restrict__ wt,
              const float* __restrict__ bias,
              const int*  __restrict__ perm,
              float* __restrict__ out)
{
    // bijective: 3072 = 8 xcd x 12 slots x 32 g  (g fastest within an XCD)
    const int bid  = blockIdx.x;
    const int xcd  = bid & 7;
    const int i    = bid >> 3;        // 0..383 within XCD
    const int g    = i & 31;          // cohort spans all 32 diagonals
    const int s    = xcd * 12 + (i >> 5);   // 0..95 = (c, mtile)
    const int c    = s >> 5;
    const int mtile = s & 31;
    const int cg   = c * 32 + g;

    const int tid  = threadIdx.x;
    const int lane = tid & 63, wv = tid >> 6;
    const int r = lane & 15, kg = lane >> 4;

    __shared__ float As[4][2048];     // 4 x 8KB ring; rows = 32 floats (128B)

    int cp = 0;
    #pragma unroll
    for (int ii = 0; ii < C_SZ; ++ii) if (perm[ii] == c) cp = ii;

    // staging: thread owns physical chunks q0 = wv*128+lane, q1 = q0+64.
    // chunk q -> row = q>>3, pos = q&7, logical k-chunk lpos = pos ^ (row&7).
    const float* g_src[2];
    #pragma unroll
    for (int j = 0; j < 2; ++j) {
        int q    = wv * 128 + j * 64 + lane;
        int row  = q >> 3;
        int lpos = (q & 7) ^ (row & 7);
        int mg   = mtile * 64 + row;
        int b    = mg >> 5, nh = mg & 31, nw = (g - nh) & 31;
        g_src[j] = x + (((size_t)(b * C_SZ + c) * IMG_SZ + nh * 16 + (lpos >> 2)) * IMG_SZ
                        + nw * 16 + (lpos & 3) * 4);
    }
    // B fragment source (lane-contiguous 16B per (ks,ni))
    const u16* bsrc = wt + (size_t)cg * 65536 + kg * 2048 + (size_t)(wv * 64 + r) * 8;

    // swizzled ds_read float offsets (involution of the source swizzle)
    const int p0 = (((2 * kg)     ^ (r & 7)) * 4);
    const int p1 = (((2 * kg + 1) ^ (r & 7)) * 4);
    const int rbase = r * 32;

    f32x4 acc[4][4] = {};
    short8 bv[2][4];                  // ping-pong, all indices literal after unroll

#define STAGE_A(t) do {                                                \
        float* d_ = &As[(t) & 3][0] + wv * 512;                        \
        gload_lds16(g_src[0] + (size_t)(t) * 1024, d_);                \
        gload_lds16(g_src[1] + (size_t)(t) * 1024, d_ + 256);          \
    } while (0)

    // ---- prologue: A(0), A(1) in flight; B(0) issued last ----
    STAGE_A(0);
    STAGE_A(1);
    #pragma unroll
    for (int ni = 0; ni < 4; ++ni)
        bv[0][ni] = gload_b128(bsrc + ni * 128);

    #pragma unroll
    for (int t = 0; t < 8; ++t) {
        // issue order: B(t+1) first, then A(t+2)
        if (t < 7) {
            #pragma unroll
            for (int ni = 0; ni < 4; ++ni)            // 4 pinned loads
                bv[(t + 1) & 1][ni] = gload_b128(bsrc + (t + 1) * 8192 + ni * 128);
        }
        if (t < 6) STAGE_A(t + 2);                    // 2 DMA

        if (t == 0 || t == 6) {
            asm volatile("s_waitcnt vmcnt(6)" ::: "memory");
        } else if (t <= 5) {
            asm volatile("s_waitcnt vmcnt(8)" ::: "memory");
        } else {
            asm volatile("s_waitcnt vmcnt(0)" ::: "memory");
        }
        __builtin_amdgcn_sched_barrier(0);
        __builtin_amdgcn_s_barrier();

        const float* lb = &As[t & 3][0];
        #pragma unroll
        for (int mi = 0; mi < 4; ++mi) {
            f32x4 v0 = *reinterpret_cast<const f32x4*>(lb + mi * 512 + rbase + p0);
            f32x4 v1 = *reinterpret_cast<const f32x4*>(lb + mi * 512 + rbase + p1);
            short8 af;
            af[0] = (short)f2bf(v0[0]); af[1] = (short)f2bf(v0[1]);
            af[2] = (short)f2bf(v0[2]); af[3] = (short)f2bf(v0[3]);
            af[4] = (short)f2bf(v1[0]); af[5] = (short)f2bf(v1[1]);
            af[6] = (short)f2bf(v1[2]); af[7] = (short)f2bf(v1[3]);
            #pragma unroll
            for (int ni = 0; ni < 4; ++ni)
                acc[mi][ni] = __builtin_amdgcn_mfma_f32_16x16x32_bf16(
                    af, bv[t & 1][ni], acc[mi][ni], 0, 0, 0);
        }
    }
#undef STAGE_A

    // ---- epilogue: bias + tanh + un-patch + channel permute ----
    const int cc = lane & 15;
    float bs[4];
    #pragma unroll
    for (int ni = 0; ni < 4; ++ni)
        bs[ni] = bias[(size_t)cg * 256 + wv * 64 + ni * 16 + cc];

    #pragma unroll
    for (int mi = 0; mi < 4; ++mi) {
        #pragma unroll
        for (int reg = 0; reg < 4; ++reg) {
            const int ml = mi * 16 + kg * 4 + reg;
            const int mg = mtile * 64 + ml;
            const int b  = mg >> 5, nh = mg & 31, nw = (g - nh) & 31;
            float* orow = out + ((size_t)(b * C_SZ + cp) * IMG_SZ + nh * 16) * IMG_SZ
                              + nw * 16 + cc;
            #pragma unroll
            for (int ni = 0; ni < 4; ++ni) {
                const int rp = wv * 4 + ni;          // patch-local row
                orow[(size_t)rp * IMG_SZ] = tanh_fast(acc[mi][ni][reg] + bs[ni]);
            }
        }
    }
}

extern "C" void kernel_launch(void* const* d_in, const int* in_sizes, int n_in,
                              void* d_out, int out_size, void* d_ws, size_t ws_size,
                              hipStream_t stream) {
    const float* x    = (const float*)d_in[0];
    const float* w    = (const float*)d_in[1];
    const float* bias = (const float*)d_in[2];
    const int*   perm = (const int*)d_in[3];
    float* out = (float*)d_out;
    u16*   wt  = (u16*)d_ws;          // 96*65536*2 = 12.6 MB scratch

    dim3 pgrid(C_SZ * 32, 8, 1);      // (96,8)
    prep_wt<<<pgrid, 256, 0, stream>>>(w, wt);

    obf_mfma<<<3072, 256, 0, stream>>>(x, wt, bias, perm, out);
}

// Round 10
// 127.613 us; speedup vs baseline: 1.3872x; 1.0374x over previous
//
#include <hip/hip_runtime.h>

// ---- problem constants ----
#define C_SZ   3
#define IMG_SZ 512
// per (c,g) GEMM: M = 64*32 = 2048, K = 256, N = 256
// Block: BM=128 x BN=256, 8 waves (2x4 grid of 64x64 wave tiles), 512 threads.
// 16 mtiles x 96 cg = 1536 blocks. Halves B (wt) re-read traffic vs BM=64.

typedef short  short8 __attribute__((ext_vector_type(8)));   // 8 bf16 (4 VGPR)
typedef float  f32x4  __attribute__((ext_vector_type(4)));
typedef unsigned short u16;
typedef u16    u16x8  __attribute__((ext_vector_type(8)));

__device__ __forceinline__ u16 f2bf(float f) {
    unsigned u = __float_as_uint(f);
    u += 0x7FFFu + ((u >> 16) & 1u);          // round-to-nearest-even
    return (u16)(u >> 16);
}

__device__ __forceinline__ float tanh_fast(float v) {
    float e = __expf(2.f * v);
    return 1.f - 2.f * __builtin_amdgcn_rcpf(e + 1.f);
}

// async 16B global->LDS DMA (lane i of the wave lands at ldsbase + i*16)
__device__ __forceinline__ void gload_lds16(const float* g, float* l) {
    __builtin_amdgcn_global_load_lds(
        (const __attribute__((address_space(1))) void*)g,
        (__attribute__((address_space(3))) void*)l, 16, 0, 0);
}

// order-pinned 16B global->VGPR load (counts in vmcnt exactly where issued)
__device__ __forceinline__ short8 gload_b128(const u16* p) {
    short8 d;
    asm volatile("global_load_dwordx4 %0, %1, off"
                 : "=v"(d) : "v"(p) : "memory");
    return d;
}

// ---------- prep: wt3[cg][kb][kg][n][e] = bf16(w[cg][kb*32+kg*8+e][n]) ----------
__global__ __launch_bounds__(256)
void prep_wt(const float* __restrict__ w, u16* __restrict__ wt) {
    const int cg = blockIdx.x;        // 0..95
    const int kb = blockIdx.y;        // 0..7
    __shared__ float T[32][260];      // +4 pad: conflict-free column gather
    const int tid = threadIdx.x;
    const float* wb = w + (size_t)cg * 65536 + (size_t)kb * 32 * 256;
    #pragma unroll
    for (int pass = 0; pass < 8; ++pass) {
        int q = pass * 256 + tid;
        int pl = q >> 6, o4 = (q & 63) * 4;
        float4 v = *reinterpret_cast<const float4*>(wb + (size_t)pl * 256 + o4);
        T[pl][o4 + 0] = v.x; T[pl][o4 + 1] = v.y;
        T[pl][o4 + 2] = v.z; T[pl][o4 + 3] = v.w;
    }
    __syncthreads();
    u16* dst = wt + ((size_t)cg * 8 + kb) * 8192;
    #pragma unroll
    for (int h0 = 0; h0 < 4; ++h0) {
        int h = h0 * 256 + tid;
        int kg = h >> 8, n = h & 255;
        u16x8 v;
        #pragma unroll
        for (int e = 0; e < 8; ++e) v[e] = f2bf(T[kg * 8 + e][n]);
        *reinterpret_cast<u16x8*>(dst + (size_t)kg * 2048 + n * 8) = v;
    }
}

// ---------- main GEMM: BM=128 x BN=256, 8 waves (each 64x64) ----------
// Round-9 dataflow (async-DMA A ring d=2, asm-pinned B d=1, counted vmcnt,
// g-fastest cohort mapping) with doubled BM to halve per-CU B bytes.
__global__ __launch_bounds__(512)
void obf_mfma(const float* __restrict__ x,
              const u16*  __restrict__ wt,
              const float* __restrict__ bias,
              const int*  __restrict__ perm,
              float* __restrict__ out)
{
    // bijective: 1536 = 8 xcd x 6 slots x 32 g  (g fastest within an XCD)
    const int bid  = blockIdx.x;
    const int xcd  = bid & 7;
    const int i    = bid >> 3;        // 0..191 within XCD
    const int g    = i & 31;          // cohort spans all 32 diagonals
    const int s    = xcd * 6 + (i >> 5);    // 0..47 = (c, mtile)
    const int c    = s >> 4;
    const int mtile = s & 15;         // 0..15 (M = 2048 / 128)
    const int cg   = c * 32 + g;

    const int tid  = threadIdx.x;
    const int lane = tid & 63, wv = tid >> 6;      // wv 0..7
    const int wr   = wv >> 2, wc = wv & 3;         // wave tile (row, col)
    const int r = lane & 15, kg = lane >> 4;

    __shared__ float As[4][4096];     // 4 x 16KB ring; rows = 32 floats (128B)

    int cp = 0;
    #pragma unroll
    for (int ii = 0; ii < C_SZ; ++ii) if (perm[ii] == c) cp = ii;

    // staging: thread owns physical chunks q0 = wv*128+lane, q1 = q0+64 (1024 total).
    // chunk q -> row = q>>3, pos = q&7, logical k-chunk lpos = pos ^ (row&7).
    const float* g_src[2];
    #pragma unroll
    for (int j = 0; j < 2; ++j) {
        int q    = wv * 128 + j * 64 + lane;
        int row  = q >> 3;            // 0..127
        int lpos = (q & 7) ^ (row & 7);
        int mg   = mtile * 128 + row;
        int b    = mg >> 5, nh = mg & 31, nw = (g - nh) & 31;
        g_src[j] = x + (((size_t)(b * C_SZ + c) * IMG_SZ + nh * 16 + (lpos >> 2)) * IMG_SZ
                        + nw * 16 + (lpos & 3) * 4);
    }
    // B fragment source (lane-contiguous 16B per (ks,ni)); wave col group wc
    const u16* bsrc = wt + (size_t)cg * 65536 + kg * 2048 + (size_t)(wc * 64 + r) * 8;

    // swizzled ds_read float offsets (involution of the source swizzle)
    const int p0 = (((2 * kg)     ^ (r & 7)) * 4);
    const int p1 = (((2 * kg + 1) ^ (r & 7)) * 4);
    const int rbase = (wr * 64 + r) * 32;          // wave row base (wr*64 % 8 == 0)

    f32x4 acc[4][4] = {};
    short8 bv[2][4];                  // ping-pong, all indices literal after unroll

#define STAGE_A(t) do {                                                \
        float* d_ = &As[(t) & 3][0] + wv * 512;                        \
        gload_lds16(g_src[0] + (size_t)(t) * 1024, d_);                \
        gload_lds16(g_src[1] + (size_t)(t) * 1024, d_ + 256);          \
    } while (0)

    // ---- prologue: A(0), A(1) in flight; B(0) issued last ----
    STAGE_A(0);
    STAGE_A(1);
    #pragma unroll
    for (int ni = 0; ni < 4; ++ni)
        bv[0][ni] = gload_b128(bsrc + ni * 128);

    #pragma unroll
    for (int t = 0; t < 8; ++t) {
        // issue order: B(t+1) first, then A(t+2)
        if (t < 7) {
            #pragma unroll
            for (int ni = 0; ni < 4; ++ni)            // 4 pinned loads
                bv[(t + 1) & 1][ni] = gload_b128(bsrc + (t + 1) * 8192 + ni * 128);
        }
        if (t < 6) STAGE_A(t + 2);                    // 2 DMA

        if (t == 0 || t == 6) {
            asm volatile("s_waitcnt vmcnt(6)" ::: "memory");
        } else if (t <= 5) {
            asm volatile("s_waitcnt vmcnt(8)" ::: "memory");
        } else {
            asm volatile("s_waitcnt vmcnt(0)" ::: "memory");
        }
        __builtin_amdgcn_sched_barrier(0);
        __builtin_amdgcn_s_barrier();

        const float* lb = &As[t & 3][0];
        #pragma unroll
        for (int mi = 0; mi < 4; ++mi) {
            f32x4 v0 = *reinterpret_cast<const f32x4*>(lb + (rbase + mi * 16 * 32) + p0);
            f32x4 v1 = *reinterpret_cast<const f32x4*>(lb + (rbase + mi * 16 * 32) + p1);
            short8 af;
            af[0] = (short)f2bf(v0[0]); af[1] = (short)f2bf(v0[1]);
            af[2] = (short)f2bf(v0[2]); af[3] = (short)f2bf(v0[3]);
            af[4] = (short)f2bf(v1[0]); af[5] = (short)f2bf(v1[1]);
            af[6] = (short)f2bf(v1[2]); af[7] = (short)f2bf(v1[3]);
            #pragma unroll
            for (int ni = 0; ni < 4; ++ni)
                acc[mi][ni] = __builtin_amdgcn_mfma_f32_16x16x32_bf16(
                    af, bv[t & 1][ni], acc[mi][ni], 0, 0, 0);
        }
    }
#undef STAGE_A

    // ---- epilogue: bias + tanh + un-patch + channel permute ----
    const int cc = lane & 15;
    float bs[4];
    #pragma unroll
    for (int ni = 0; ni < 4; ++ni)
        bs[ni] = bias[(size_t)cg * 256 + wc * 64 + ni * 16 + cc];

    #pragma unroll
    for (int mi = 0; mi < 4; ++mi) {
        #pragma unroll
        for (int reg = 0; reg < 4; ++reg) {
            const int ml = mi * 16 + kg * 4 + reg;       // wave-local row 0..63
            const int mg = mtile * 128 + wr * 64 + ml;
            const int b  = mg >> 5, nh = mg & 31, nw = (g - nh) & 31;
            float* orow = out + ((size_t)(b * C_SZ + cp) * IMG_SZ + nh * 16) * IMG_SZ
                              + nw * 16 + cc;
            #pragma unroll
            for (int ni = 0; ni < 4; ++ni) {
                const int rp = wc * 4 + ni;              // patch-local row
                orow[(size_t)rp * IMG_SZ] = tanh_fast(acc[mi][ni][reg] + bs[ni]);
            }
        }
    }
}

extern "C" void kernel_launch(void* const* d_in, const int* in_sizes, int n_in,
                              void* d_out, int out_size, void* d_ws, size_t ws_size,
                              hipStream_t stream) {
    const float* x    = (const float*)d_in[0];
    const float* w    = (const float*)d_in[1];
    const float* bias = (const float*)d_in[2];
    const int*   perm = (const int*)d_in[3];
    float* out = (float*)d_out;
    u16*   wt  = (u16*)d_ws;          // 96*65536*2 = 12.6 MB scratch

    dim3 pgrid(C_SZ * 32, 8, 1);      // (96,8)
    prep_wt<<<pgrid, 256, 0, stream>>>(w, wt);

    obf_mfma<<<1536, 512, 0, stream>>>(x, wt, bias, perm, out);
}

// Round 11
// 126.223 us; speedup vs baseline: 1.4025x; 1.0110x over previous
//
#include <hip/hip_runtime.h>

// ---- problem constants ----
#define C_SZ   3
#define IMG_SZ 512
// per (c,g) GEMM: M = 64*32 = 2048, K = 256, N = 256
// Block: BM=128 x BN=256, 8 waves (2x4 grid of 64x64 wave tiles), 512 threads.
// 16 mtiles x 96 cg = 1536 blocks (halved B re-read vs BM=64).

typedef short  short8 __attribute__((ext_vector_type(8)));   // 8 bf16 (4 VGPR)
typedef float  f32x4  __attribute__((ext_vector_type(4)));
typedef unsigned short u16;
typedef u16    u16x8  __attribute__((ext_vector_type(8)));

__device__ __forceinline__ u16 f2bf(float f) {
    unsigned u = __float_as_uint(f);
    u += 0x7FFFu + ((u >> 16) & 1u);          // round-to-nearest-even
    return (u16)(u >> 16);
}

__device__ __forceinline__ float tanh_fast(float v) {
    float e = __expf(2.f * v);
    return 1.f - 2.f * __builtin_amdgcn_rcpf(e + 1.f);
}

// async 16B global->LDS DMA (lane i of the wave lands at ldsbase + i*16)
__device__ __forceinline__ void gload_lds16(const float* g, float* l) {
    __builtin_amdgcn_global_load_lds(
        (const __attribute__((address_space(1))) void*)g,
        (__attribute__((address_space(3))) void*)l, 16, 0, 0);
}

// order-pinned 16B global->VGPR load (counts in vmcnt exactly where issued)
__device__ __forceinline__ short8 gload_b128(const u16* p) {
    short8 d;
    asm volatile("global_load_dwordx4 %0, %1, off"
                 : "=v"(d) : "v"(p) : "memory");
    return d;
}

// ---------- prep: wt3[cg][kb][kg][n][e] = bf16(w[cg][kb*32+kg*8+e][n]) ----------
__global__ __launch_bounds__(256)
void prep_wt(const float* __restrict__ w, u16* __restrict__ wt) {
    const int cg = blockIdx.x;        // 0..95
    const int kb = blockIdx.y;        // 0..7
    __shared__ float T[32][260];      // +4 pad: conflict-free column gather
    const int tid = threadIdx.x;
    const float* wb = w + (size_t)cg * 65536 + (size_t)kb * 32 * 256;
    #pragma unroll
    for (int pass = 0; pass < 8; ++pass) {
        int q = pass * 256 + tid;
        int pl = q >> 6, o4 = (q & 63) * 4;
        float4 v = *reinterpret_cast<const float4*>(wb + (size_t)pl * 256 + o4);
        T[pl][o4 + 0] = v.x; T[pl][o4 + 1] = v.y;
        T[pl][o4 + 2] = v.z; T[pl][o4 + 3] = v.w;
    }
    __syncthreads();
    u16* dst = wt + ((size_t)cg * 8 + kb) * 8192;
    #pragma unroll
    for (int h0 = 0; h0 < 4; ++h0) {
        int h = h0 * 256 + tid;
        int kg = h >> 8, n = h & 255;
        u16x8 v;
        #pragma unroll
        for (int e = 0; e < 8; ++e) v[e] = f2bf(T[kg * 8 + e][n]);
        *reinterpret_cast<u16x8*>(dst + (size_t)kg * 2048 + n * 8) = v;
    }
}

// ---------- main GEMM: BM=128 x BN=256, 8 waves (each 64x64) ----------
// r10 tile (halved B bytes) + r8 pipeline (ring-3, d=1, vmcnt(6) -> 3 blocks/CU)
// + SWAPPED MFMA operands: acc holds C^T so the reg-axis runs along output
// columns -> float4 epilogue stores (16/thread instead of 64 scalar).
__global__ __launch_bounds__(512)
void obf_mfma(const float* __restrict__ x,
              const u16*  __restrict__ wt,
              const float* __restrict__ bias,
              const int*  __restrict__ perm,
              float* __restrict__ out)
{
    // bijective: 1536 = 8 xcd x 6 slots x 32 g  (g fastest within an XCD)
    const int bid  = blockIdx.x;
    const int xcd  = bid & 7;
    const int i    = bid >> 3;        // 0..191 within XCD
    const int g    = i & 31;          // cohort spans all 32 diagonals
    const int s    = xcd * 6 + (i >> 5);    // 0..47 = (c, mtile)
    const int c    = s >> 4;
    const int mtile = s & 15;         // 0..15 (M = 2048 / 128)
    const int cg   = c * 32 + g;

    const int tid  = threadIdx.x;
    const int lane = tid & 63, wv = tid >> 6;      // wv 0..7
    const int wr   = wv >> 2, wc = wv & 3;         // wave tile (row, col)
    const int r = lane & 15, kg = lane >> 4;

    __shared__ float As[3][4096];     // ring: 3 x 16KB; rows = 32 floats (128B)

    int cp = 0;
    #pragma unroll
    for (int ii = 0; ii < C_SZ; ++ii) if (perm[ii] == c) cp = ii;

    // staging: thread owns physical chunks q0 = wv*128+lane, q1 = q0+64 (1024 total).
    // chunk q -> row = q>>3, pos = q&7, logical k-chunk lpos = pos ^ (row&7).
    const float* g_src[2];
    #pragma unroll
    for (int j = 0; j < 2; ++j) {
        int q    = wv * 128 + j * 64 + lane;
        int row  = q >> 3;            // 0..127
        int lpos = (q & 7) ^ (row & 7);
        int mg   = mtile * 128 + row;
        int b    = mg >> 5, nh = mg & 31, nw = (g - nh) & 31;
        g_src[j] = x + (((size_t)(b * C_SZ + c) * IMG_SZ + nh * 16 + (lpos >> 2)) * IMG_SZ
                        + nw * 16 + (lpos & 3) * 4);
    }
    // B fragment source (lane-contiguous 16B per (ks,ni)); wave col group wc
    const u16* bsrc = wt + (size_t)cg * 65536 + kg * 2048 + (size_t)(wc * 64 + r) * 8;

    // swizzled ds_read float offsets (involution of the source swizzle)
    const int p0 = (((2 * kg)     ^ (r & 7)) * 4);
    const int p1 = (((2 * kg + 1) ^ (r & 7)) * 4);
    const int rbase = (wr * 64 + r) * 32;          // wave row base (wr*64 % 8 == 0)

    f32x4 acc[4][4] = {};             // acc[mi][ni]: C^T fragment, reg axis = n
    short8 bv[2][4];                  // ping-pong, all indices literal after unroll

#define STAGE_A(t) do {                                                \
        float* d_ = &As[(t) % 3][0] + wv * 512;                        \
        gload_lds16(g_src[0] + (size_t)(t) * 1024, d_);                \
        gload_lds16(g_src[1] + (size_t)(t) * 1024, d_ + 256);          \
    } while (0)

    // ---- prologue: A(0) in flight; B(0) issued after ----
    STAGE_A(0);
    #pragma unroll
    for (int ni = 0; ni < 4; ++ni)
        bv[0][ni] = gload_b128(bsrc + ni * 128);

    #pragma unroll
    for (int t = 0; t < 8; ++t) {
        if (t < 7) {
            STAGE_A(t + 1);                           // 2 DMA
            #pragma unroll
            for (int ni = 0; ni < 4; ++ni)            // 4 pinned loads
                bv[(t + 1) & 1][ni] = gload_b128(bsrc + (t + 1) * 8192 + ni * 128);
            asm volatile("s_waitcnt vmcnt(6)" ::: "memory");  // drain stage t only
        } else {
            asm volatile("s_waitcnt vmcnt(0)" ::: "memory");
        }
        __builtin_amdgcn_sched_barrier(0);
        __builtin_amdgcn_s_barrier();

        const float* lb = &As[t % 3][0];
        #pragma unroll
        for (int mi = 0; mi < 4; ++mi) {
            f32x4 v0 = *reinterpret_cast<const f32x4*>(lb + (rbase + mi * 16 * 32) + p0);
            f32x4 v1 = *reinterpret_cast<const f32x4*>(lb + (rbase + mi * 16 * 32) + p1);
            short8 af;
            af[0] = (short)f2bf(v0[0]); af[1] = (short)f2bf(v0[1]);
            af[2] = (short)f2bf(v0[2]); af[3] = (short)f2bf(v0[3]);
            af[4] = (short)f2bf(v1[0]); af[5] = (short)f2bf(v1[1]);
            af[6] = (short)f2bf(v1[2]); af[7] = (short)f2bf(v1[3]);
            #pragma unroll
            for (int ni = 0; ni < 4; ++ni)
                acc[mi][ni] = __builtin_amdgcn_mfma_f32_16x16x32_bf16(
                    bv[t & 1][ni], af, acc[mi][ni], 0, 0, 0);   // SWAPPED -> C^T
        }
    }
#undef STAGE_A

    // ---- epilogue: bias + tanh + un-patch + channel permute (float4 stores) ----
    // acc[mi][ni][reg]: m = mtile*128 + wr*64 + mi*16 + r
    //                   o = wc*64 + ni*16 + kg*4 + reg  (4 consecutive cols)
    const float* bb = bias + (size_t)cg * 256 + wc * 64 + kg * 4;
    float4 bsv[4];
    #pragma unroll
    for (int ni = 0; ni < 4; ++ni)
        bsv[ni] = *reinterpret_cast<const float4*>(bb + ni * 16);

    #pragma unroll
    for (int mi = 0; mi < 4; ++mi) {
        const int mg = mtile * 128 + wr * 64 + mi * 16 + r;
        const int b  = mg >> 5, nh = mg & 31, nw = (g - nh) & 31;
        float* pbase = out + ((size_t)(b * C_SZ + cp) * IMG_SZ + nh * 16) * IMG_SZ
                           + nw * 16 + kg * 4;
        #pragma unroll
        for (int ni = 0; ni < 4; ++ni) {
            const int rp = wc * 4 + ni;              // patch-local row
            float4 v;
            v.x = tanh_fast(acc[mi][ni][0] + bsv[ni].x);
            v.y = tanh_fast(acc[mi][ni][1] + bsv[ni].y);
            v.z = tanh_fast(acc[mi][ni][2] + bsv[ni].z);
            v.w = tanh_fast(acc[mi][ni][3] + bsv[ni].w);
            *reinterpret_cast<float4*>(pbase + (size_t)rp * IMG_SZ) = v;
        }
    }
}

extern "C" void kernel_launch(void* const* d_in, const int* in_sizes, int n_in,
                              void* d_out, int out_size, void* d_ws, size_t ws_size,
                              hipStream_t stream) {
    const float* x    = (const float*)d_in[0];
    const float* w    = (const float*)d_in[1];
    const float* bias = (const float*)d_in[2];
    const int*   perm = (const int*)d_in[3];
    float* out = (float*)d_out;
    u16*   wt  = (u16*)d_ws;          // 96*65536*2 = 12.6 MB scratch

    dim3 pgrid(C_SZ * 32, 8, 1);      // (96,8)
    prep_wt<<<pgrid, 256, 0, stream>>>(w, wt);

    obf_mfma<<<1536, 512, 0, stream>>>(x, wt, bias, perm, out);
}